// Round 15
// baseline (3052.309 us; speedup 1.0000x reference)
//
#include <hip/hip_runtime.h>
#include <hip/hip_bf16.h>

typedef __attribute__((ext_vector_type(8))) short short8;
typedef __attribute__((ext_vector_type(8))) unsigned short ushort8;
typedef __attribute__((ext_vector_type(4))) float f32x4;
typedef __attribute__((ext_vector_type(4))) int int4v;
typedef __attribute__((ext_vector_type(4))) short short4v;

#define NB 256      // batch rows
#define NS 256      // timesteps
#define NH 512      // hidden/state dim (D == H == 512)
#define NOUT 128
#define XROW 513    // x last-dim stride

#define NCL 16      // clusters (16 batch rows each)
#define RPC 16      // rows per cluster
#define NHALF 256   // u-dims per block (half of M)
#define LPAD 520    // padded LDS row (bf16): 1040B stride

// ---- workspace layout (bytes) ----
#define OFF_DTS   0
#define OFF_Y0    4096
#define OFF_U0    (OFF_Y0 + NB*NH*4)
#define OFF_M     (OFF_U0 + NB*NH*4)
#define OFF_C     (OFF_M + NH*NH*2)
#define OFF_P     (OFF_C + 4096)
#define OFF_HG    (OFF_P + NOUT*NH*4)                // 16 cl * 2 par * 16*512 bf16
#define HG_BYTES  (NCL*2*RPC*NH*2)
#define OFF_HACC  (OFF_HG + HG_BYTES)
#define OFF_FLAGS (OFF_HACC + NB*NH*4)               // 16 cl * 16 words

static __device__ __forceinline__ unsigned bf16bits(float x) {
  return (unsigned)__builtin_bit_cast(unsigned short, __float2bfloat16(x));
}

// Cross-block traffic: sc0 sc1 (device coherence point) — R4-proven primitives.
static __device__ __forceinline__ void g_store8(void* addr, short4v v) {
  asm volatile("global_store_dwordx2 %0, %1, off sc0 sc1" :: "v"(addr), "v"(v) : "memory");
}
static __device__ __forceinline__ void g_store4(void* addr, unsigned v) {
  asm volatile("global_store_dword %0, %1, off sc0 sc1" :: "v"(addr), "v"(v) : "memory");
}
static __device__ __forceinline__ unsigned g_load4w(const void* addr) {  // fused load+wait
  unsigned v;
  asm volatile("global_load_dword %0, %1, off sc0 sc1\n\ts_waitcnt vmcnt(0)"
               : "=v"(v) : "v"(addr) : "memory");
  return v;
}
static __device__ __forceinline__ unsigned g_load4_nw(const void* addr) {  // no wait (speculative)
  unsigned v;
  asm volatile("global_load_dword %0, %1, off sc0 sc1" : "=v"(v) : "v"(addr) : "memory");
  return v;
}
static __device__ __forceinline__ void wait_vm0() {
  asm volatile("s_waitcnt vmcnt(0)" ::: "memory");
}
// lgkm-only barrier: LDS visibility WITHOUT draining global stores.
static __device__ __forceinline__ void bar_lgkm() {
  asm volatile("s_waitcnt lgkmcnt(0)" ::: "memory");
  __builtin_amdgcn_s_barrier();
}

// fast tanh: (e^{2x}-1)/(e^{2x}+1), clamp |x|<=15  (R4-proven accuracy)
static __device__ __forceinline__ float tanh_fast(float x) {
  x = fminf(fmaxf(x, -15.f), 15.f);
  float e = __expf(2.f * x);
  return (e - 1.f) * __builtin_amdgcn_rcpf(e + 1.f);
}

// -------------------- small prep kernels --------------------

__global__ void k_dts(const float* __restrict__ x, float* __restrict__ dts) {
  int s = threadIdx.x;
  if (s < NS - 1) dts[s] = x[(s + 1) * XROW] - x[s * XROW];
  if (s == NS - 1) dts[NS - 1] = x[(NS - 1) * XROW] - x[0];  // sum_dt (telescoping)
}

__global__ void k_y0(const float* __restrict__ x, float* __restrict__ y0) {
  int b = blockIdx.x;
  const float* src = x + (size_t)b * NS * XROW + (size_t)(NS - 1) * XROW + 1;
  for (int d = threadIdx.x; d < NH; d += blockDim.x) y0[b * NH + d] = src[d];
}

__global__ void k_c(const float* __restrict__ W1, const float* __restrict__ b2,
                    float* __restrict__ c) {
  int i = blockIdx.x * blockDim.x + threadIdx.x;
  if (i < NH) {
    float s = 0.f;
    for (int d = 0; d < NH; ++d) s += W1[i * NH + d] * b2[d];
    c[i] = s;
  }
}

__global__ void k_mm_nn_bf16(const float* __restrict__ A, const float* __restrict__ Bm,
                             __hip_bfloat16* __restrict__ C, int N, int K) {
  __shared__ float As[16][17], Bs[16][17];
  int tx = threadIdx.x & 15, ty = threadIdx.x >> 4;
  int m = blockIdx.y * 16 + ty, n = blockIdx.x * 16 + tx;
  float acc = 0.f;
  for (int k0 = 0; k0 < K; k0 += 16) {
    As[ty][tx] = A[m * K + k0 + tx];
    Bs[ty][tx] = Bm[(size_t)(k0 + ty) * N + n];
    __syncthreads();
#pragma unroll
    for (int kk = 0; kk < 16; ++kk) acc += As[ty][kk] * Bs[kk][tx];
    __syncthreads();
  }
  C[m * N + n] = __float2bfloat16(acc);
}

__global__ void k_mm_nn_f32(const float* __restrict__ A, const float* __restrict__ Bm,
                            float* __restrict__ C, int N, int K) {
  __shared__ float As[16][17], Bs[16][17];
  int tx = threadIdx.x & 15, ty = threadIdx.x >> 4;
  int m = blockIdx.y * 16 + ty, n = blockIdx.x * 16 + tx;
  float acc = 0.f;
  for (int k0 = 0; k0 < K; k0 += 16) {
    As[ty][tx] = A[m * K + k0 + tx];
    Bs[ty][tx] = Bm[(size_t)(k0 + ty) * N + n];
    __syncthreads();
#pragma unroll
    for (int kk = 0; kk < 16; ++kk) acc += As[ty][kk] * Bs[kk][tx];
    __syncthreads();
  }
  C[m * N + n] = acc;
}

__global__ void k_mm_nt_f32(const float* __restrict__ A, const float* __restrict__ Bm,
                            float* __restrict__ C, int N, int K) {
  __shared__ float As[16][17], Bs[16][17];
  int tx = threadIdx.x & 15, ty = threadIdx.x >> 4;
  int m = blockIdx.y * 16 + ty;
  int n0 = blockIdx.x * 16;
  float acc = 0.f;
  for (int k0 = 0; k0 < K; k0 += 16) {
    As[ty][tx] = A[m * K + k0 + tx];
    Bs[ty][tx] = Bm[(size_t)(n0 + ty) * K + k0 + tx];
    __syncthreads();
#pragma unroll
    for (int kk = 0; kk < 16; ++kk) acc += As[ty][kk] * Bs[tx][kk];
    __syncthreads();
  }
  C[m * N + n0 + tx] = acc;
}

// -------------------- main ODE integration kernel --------------------
// 32 blocks = 16 clusters x 2 halves; pair (bx, bx+16) shares bx mod 8 (XCD).
// Each 256-thread block (4 waves, 1 wave/SIMD via __launch_bounds__(256,1),
// 512-reg unified budget) holds HALF of M in registers: wave w owns rows
// [hb*256 + w*64, +64) as Mreg[4][16] short8 (256 regs/lane, static indices;
// chunk-reordered so i=0..7 are OWN-half K-chunks, i=8..15 PEER-half).
// Exchange protocol = R4/R13/R14 VERBATIM (4-for-4 liveness): bf16 publish ->
// lgkm-bar (stores in flight) -> own-half MFMA (8 chunks; covers store drain)
// -> vmcnt(0) residual ack -> per-wave flag -> speculative-then-proven poll
// (PEER block only: 1 peer, not 3) -> ONE fused-asm gather (2 loads + wait)
// -> bar -> peer-half MFMA -> folded RK4. Liveness is data-independent.

__global__ __launch_bounds__(256, 1) void k_main(
    const float* __restrict__ u0, const __hip_bfloat16* __restrict__ Mg,
    const float* __restrict__ cg, const float* __restrict__ b1g,
    const float* __restrict__ dtsg,
    __hip_bfloat16* __restrict__ hG, float* __restrict__ Hacc,
    unsigned int* __restrict__ flags)
{
  __shared__ __hip_bfloat16 hlds[RPC][LPAD];   // 16.25 KB
  __shared__ float dtl[NS];

  const int tid = threadIdx.x;
  const int bx = blockIdx.x;
  const int cl = bx & 15, hb = bx >> 4;       // cluster, half; pair shares mod 8
  const int lane = tid & 63, wv = tid >> 6;
  const int r = lane & 15, g4 = lane >> 4;
  const int row0 = cl * RPC;
  const int rowbase = hb * NHALF + wv * 64;   // this wave's 64 M-rows
  const int ownbase = hb * NHALF;             // own-half dim offset
  const int peerbase = NHALF - ownbase;       // peer-half dim offset (256-hb*256... = (1-hb)*256)
  const int rr = tid >> 4, sl = tid & 15;     // gather assignment

  // ---- M fragments into registers, chunk-reordered: i=0..7 own half,
  // i=8..15 peer half. qg = (i<8) ? hb*8+i : (1-hb)*8 + (i-8). ----
  short8 Mreg[4][16];
#pragma unroll
  for (int t = 0; t < 4; ++t)
#pragma unroll
    for (int i = 0; i < 16; ++i) {
      int qg = (i < 8) ? (hb * 8 + i) : ((1 - hb) * 8 + (i - 8));
      Mreg[t][i] = *(const short8*)(Mg + (size_t)(rowbase + t * 16 + r) * NH
                                    + qg * 32 + g4 * 8);
    }
  if (tid < NS) dtl[tid] = dtsg[tid];

  // per-lane state: (udim = rowbase + t*16 + g4*4 + j, batch row = row0 + r)
  float u[4][4], du[4][4], Ht[4][4], hr[4][4], wp[4][4], b1r[4][4], cr[4][4];
#pragma unroll
  for (int t = 0; t < 4; ++t)
#pragma unroll
    for (int j = 0; j < 4; ++j) {
      int ud = rowbase + t * 16 + g4 * 4 + j;
      u[t][j] = u0[(row0 + r) * NH + ud];
      b1r[t][j] = b1g[ud];
      cr[t][j] = cg[ud];
      Ht[t][j] = 0.f; wp[t][j] = 0.f; du[t][j] = 0.f;
    }
  __syncthreads();

  unsigned int* flg = flags + cl * 16;        // 8 per-wave flag words used
  const unsigned int* fp = flg + (lane & 7);
  const bool ownlane = (((lane & 7) >> 2) == hb);   // own block's flag words

  int sidx = 0;
  for (int step = 0; step < NS - 1; ++step) {
    float dt = dtl[step];
#pragma unroll 1
    for (int st = 0; st < 4; ++st, ++sidx) {
      float gam = (st == 0) ? 0.f : ((st == 3) ? dt : 0.5f * dt);
      // h = tanh(u + gam*w_prev + b1)
#pragma unroll
      for (int t = 0; t < 4; ++t)
#pragma unroll
        for (int j = 0; j < 4; ++j)
          hr[t][j] = tanh_fast(u[t][j] + gam * wp[t][j] + b1r[t][j]);

      int par = sidx & 1;
      __hip_bfloat16* hgp = hG + (size_t)(cl * 2 + par) * RPC * NH;
      // publish own h (global stores stay in flight; LDS for own-half MFMA)
#pragma unroll
      for (int t = 0; t < 4; ++t) {
        short4v pk;
        pk.x = (short)bf16bits(hr[t][0]);
        pk.y = (short)bf16bits(hr[t][1]);
        pk.z = (short)bf16bits(hr[t][2]);
        pk.w = (short)bf16bits(hr[t][3]);
        int col = rowbase + t * 16 + g4 * 4;
        g_store8(hgp + r * NH + col, pk);
        *(short4v*)&hlds[r][col] = pk;
      }
      bar_lgkm();                    // own h visible in LDS; stores in flight

      unsigned tgt = (unsigned)(sidx + 1);
      unsigned specv = g_load4_nw(fp);   // speculative peer-flag load

      // own-half MFMA (A from registers; 8 chunks — store drain underneath)
      f32x4 acc[4];
#pragma unroll
      for (int t = 0; t < 4; ++t) acc[t] = (f32x4){0.f, 0.f, 0.f, 0.f};
#pragma unroll
      for (int i = 0; i < 8; ++i) {
        short8 bf = *(const short8*)&hlds[r][ownbase + i * 32 + g4 * 8];
        acc[0] = __builtin_amdgcn_mfma_f32_16x16x32_bf16(Mreg[0][i], bf, acc[0], 0, 0, 0);
        acc[1] = __builtin_amdgcn_mfma_f32_16x16x32_bf16(Mreg[1][i], bf, acc[1], 0, 0, 0);
        acc[2] = __builtin_amdgcn_mfma_f32_16x16x32_bf16(Mreg[2][i], bf, acc[2], 0, 0, 0);
        acc[3] = __builtin_amdgcn_mfma_f32_16x16x32_bf16(Mreg[3][i], bf, acc[3], 0, 0, 0);
      }

      wait_vm0();                        // ack residual + spec load complete
      __builtin_amdgcn_sched_barrier(0); // keep spec check after the wait
      if (lane == 0) g_store4(flg + hb * 4 + wv, tgt);   // per-wave flag

      // peers-only check of speculative value; miss -> proven fused poll loop
      if (!__all((int)(ownlane || (specv >= tgt)))) {
        for (;;) {
          unsigned v = g_load4w(fp);
          if (__all((int)(ownlane || (v >= tgt)))) break;
          __builtin_amdgcn_s_sleep(1);
        }
      }

      // gather peer 8KB: ONE fused asm (2 loads + wait), then LDS
      {
        int4v d0, d1;
        const __hip_bfloat16* hb0 = hgp + rr * NH + peerbase + sl * 16;
        const void* a0 = hb0;
        const void* a1 = hb0 + 8;
        asm volatile(
            "global_load_dwordx4 %0, %2, off sc0 sc1\n\t"
            "global_load_dwordx4 %1, %3, off sc0 sc1\n\t"
            "s_waitcnt vmcnt(0)"
            : "=&v"(d0), "=&v"(d1)
            : "v"(a0), "v"(a1)
            : "memory");
        *(int4v*)&hlds[rr][peerbase + sl * 16] = d0;
        *(int4v*)&hlds[rr][peerbase + sl * 16 + 8] = d1;
      }
      __syncthreads();                   // peer h visible

      // peer-half MFMA (A from registers, static indices)
#pragma unroll
      for (int i = 8; i < 16; ++i) {
        short8 bf = *(const short8*)&hlds[r][peerbase + (i - 8) * 32 + g4 * 8];
        acc[0] = __builtin_amdgcn_mfma_f32_16x16x32_bf16(Mreg[0][i], bf, acc[0], 0, 0, 0);
        acc[1] = __builtin_amdgcn_mfma_f32_16x16x32_bf16(Mreg[1][i], bf, acc[1], 0, 0, 0);
        acc[2] = __builtin_amdgcn_mfma_f32_16x16x32_bf16(Mreg[2][i], bf, acc[2], 0, 0, 0);
        acc[3] = __builtin_amdgcn_mfma_f32_16x16x32_bf16(Mreg[3][i], bf, acc[3], 0, 0, 0);
      }

      // folded RK4: du += cw*w ; Ht += (dt/6)*cw*h ; wp = w ; st3: u += (dt/6)*du
      {
        float cw = (st == 0 || st == 3) ? 1.f : 2.f;
        float f6 = dt * (1.f / 6.f);
        float f6c = f6 * cw;
#pragma unroll
        for (int t = 0; t < 4; ++t)
#pragma unroll
          for (int j = 0; j < 4; ++j) {
            float wc = acc[t][j] + cr[t][j];
            du[t][j] = (st == 0) ? wc : du[t][j] + cw * wc;
            Ht[t][j] += f6c * hr[t][j];
            wp[t][j] = wc;
          }
        if (st == 3) {
#pragma unroll
          for (int t = 0; t < 4; ++t)
#pragma unroll
            for (int j = 0; j < 4; ++j)
              u[t][j] += f6 * du[t][j];
        }
      }
    }
  }

  // write out H accumulator
#pragma unroll
  for (int t = 0; t < 4; ++t)
#pragma unroll
    for (int j = 0; j < 4; ++j)
      Hacc[(row0 + r) * NH + rowbase + t * 16 + g4 * 4 + j] = Ht[t][j];
}

// -------------------- epilogue --------------------
__global__ void k_epi(const float* __restrict__ y0, const float* __restrict__ Hacc,
                      const float* __restrict__ P, const float* __restrict__ Wout,
                      const float* __restrict__ b2, const float* __restrict__ bout,
                      const float* __restrict__ dtsg, float* __restrict__ out)
{
  __shared__ float ys[NH], hs[NH];
  int rr = blockIdx.x, o = threadIdx.x;
  float sdt = dtsg[NS - 1];
  for (int i = threadIdx.x; i < NH; i += blockDim.x) {
    ys[i] = y0[rr * NH + i] + sdt * b2[i];
    hs[i] = Hacc[rr * NH + i];
  }
  __syncthreads();
  float s = bout[o];
  const float* wr = Wout + o * NH;
  const float* pr = P + o * NH;
  for (int d = 0; d < NH; ++d) s += wr[d] * ys[d];
  for (int h = 0; h < NH; ++h) s += pr[h] * hs[h];
  out[rr * NOUT + o] = s;
}

// -------------------- launch --------------------

extern "C" void kernel_launch(void* const* d_in, const int* in_sizes, int n_in,
                              void* d_out, int out_size, void* d_ws, size_t ws_size,
                              hipStream_t stream) {
  const float* x    = (const float*)d_in[0];
  const float* W1   = (const float*)d_in[1];
  const float* b1   = (const float*)d_in[2];
  const float* W2   = (const float*)d_in[3];
  const float* b2   = (const float*)d_in[4];
  const float* Wout = (const float*)d_in[5];
  const float* bout = (const float*)d_in[6];
  float* out = (float*)d_out;

  char* ws = (char*)d_ws;
  float*          dts  = (float*)(ws + OFF_DTS);
  float*          y0   = (float*)(ws + OFF_Y0);
  float*          u0   = (float*)(ws + OFF_U0);
  __hip_bfloat16* Mbf  = (__hip_bfloat16*)(ws + OFF_M);
  float*          cvec = (float*)(ws + OFF_C);
  float*          P    = (float*)(ws + OFF_P);
  __hip_bfloat16* hG   = (__hip_bfloat16*)(ws + OFF_HG);
  float*          Hac  = (float*)(ws + OFF_HACC);
  unsigned int*   flg  = (unsigned int*)(ws + OFF_FLAGS);

  hipMemsetAsync(flg, 0, NCL * 16 * 4, stream);   // monotonic flags start at 0

  k_dts<<<1, 256, 0, stream>>>(x, dts);
  k_y0 <<<NB, 256, 0, stream>>>(x, y0);
  k_c  <<<2, 256, 0, stream>>>(W1, b2, cvec);
  k_mm_nn_bf16<<<dim3(32, 32), 256, 0, stream>>>(W1, W2, Mbf, NH, NH);
  k_mm_nt_f32<<<dim3(32, 16), 256, 0, stream>>>(y0, W1, u0, NH, NH);
  k_mm_nn_f32<<<dim3(32, 8), 256, 0, stream>>>(Wout, W2, P, NH, NH);

  k_main<<<NCL * 2, 256, 0, stream>>>(u0, Mbf, cvec, b1, dts, hG, Hac, flg);

  k_epi<<<NB, NOUT, 0, stream>>>(y0, Hac, P, Wout, b2, bout, dts, out);
}

// Round 16
// 2463.849 us; speedup vs baseline: 1.2388x; 1.2388x over previous
//
#include <hip/hip_runtime.h>
#include <hip/hip_bf16.h>

typedef __attribute__((ext_vector_type(8))) short short8;
typedef __attribute__((ext_vector_type(8))) unsigned short ushort8;
typedef __attribute__((ext_vector_type(4))) float f32x4;
typedef __attribute__((ext_vector_type(4))) int int4v;
typedef __attribute__((ext_vector_type(4))) short short4v;

#define NB 256      // batch rows
#define NS 256      // timesteps
#define NH 512      // hidden/state dim (D == H == 512)
#define NOUT 128
#define XROW 513    // x last-dim stride

#define NCL 16      // clusters
#define RPC 16      // rows per cluster
#define BPC 4       // blocks per cluster
#define UBS 128     // u-dims per block
#define LPAD 520    // padded LDS row (bf16): 1040B stride

// ---- workspace layout (bytes) ----
#define OFF_DTS   0
#define OFF_Y0    4096
#define OFF_U0    (OFF_Y0 + NB*NH*4)
#define OFF_M     (OFF_U0 + NB*NH*4)
#define OFF_C     (OFF_M + NH*NH*2)
#define OFF_P     (OFF_C + 4096)
#define OFF_HG    (OFF_P + NOUT*NH*4)                // 16 cl * 2 par * 16*512 bf16
#define HG_BYTES  (NCL*2*RPC*NH*2)
#define OFF_HACC  (OFF_HG + HG_BYTES)
#define OFF_FLAGS (OFF_HACC + NB*NH*4)               // 16 cl * 32 words

static __device__ __forceinline__ unsigned bf16bits(float x) {
  return (unsigned)__builtin_bit_cast(unsigned short, __float2bfloat16(x));
}

// Cross-block traffic: sc0 sc1 (device coherence point) — R4-proven primitives.
static __device__ __forceinline__ void g_store8(void* addr, short4v v) {
  asm volatile("global_store_dwordx2 %0, %1, off sc0 sc1" :: "v"(addr), "v"(v) : "memory");
}
static __device__ __forceinline__ void g_store4(void* addr, unsigned v) {
  asm volatile("global_store_dword %0, %1, off sc0 sc1" :: "v"(addr), "v"(v) : "memory");
}
static __device__ __forceinline__ unsigned g_load4w(const void* addr) {  // fused load+wait
  unsigned v;
  asm volatile("global_load_dword %0, %1, off sc0 sc1\n\ts_waitcnt vmcnt(0)"
               : "=v"(v) : "v"(addr) : "memory");
  return v;
}
static __device__ __forceinline__ unsigned g_load4_nw(const void* addr) {  // no wait (speculative)
  unsigned v;
  asm volatile("global_load_dword %0, %1, off sc0 sc1" : "=v"(v) : "v"(addr) : "memory");
  return v;
}
static __device__ __forceinline__ void wait_vm0() {
  asm volatile("s_waitcnt vmcnt(0)" ::: "memory");
}
// lgkm-only barrier: LDS visibility WITHOUT draining global stores.
static __device__ __forceinline__ void bar_lgkm() {
  asm volatile("s_waitcnt lgkmcnt(0)" ::: "memory");
  __builtin_amdgcn_s_barrier();
}

// fast tanh: (e^{2x}-1)/(e^{2x}+1), clamp |x|<=15  (R4-proven accuracy)
static __device__ __forceinline__ float tanh_fast(float x) {
  x = fminf(fmaxf(x, -15.f), 15.f);
  float e = __expf(2.f * x);
  return (e - 1.f) * __builtin_amdgcn_rcpf(e + 1.f);
}

// -------------------- small prep kernels --------------------

__global__ void k_dts(const float* __restrict__ x, float* __restrict__ dts) {
  int s = threadIdx.x;
  if (s < NS - 1) dts[s] = x[(s + 1) * XROW] - x[s * XROW];
  if (s == NS - 1) dts[NS - 1] = x[(NS - 1) * XROW] - x[0];  // sum_dt (telescoping)
}

__global__ void k_y0(const float* __restrict__ x, float* __restrict__ y0) {
  int b = blockIdx.x;
  const float* src = x + (size_t)b * NS * XROW + (size_t)(NS - 1) * XROW + 1;
  for (int d = threadIdx.x; d < NH; d += blockDim.x) y0[b * NH + d] = src[d];
}

__global__ void k_c(const float* __restrict__ W1, const float* __restrict__ b2,
                    float* __restrict__ c) {
  int i = blockIdx.x * blockDim.x + threadIdx.x;
  if (i < NH) {
    float s = 0.f;
    for (int d = 0; d < NH; ++d) s += W1[i * NH + d] * b2[d];
    c[i] = s;
  }
}

__global__ void k_mm_nn_bf16(const float* __restrict__ A, const float* __restrict__ Bm,
                             __hip_bfloat16* __restrict__ C, int N, int K) {
  __shared__ float As[16][17], Bs[16][17];
  int tx = threadIdx.x & 15, ty = threadIdx.x >> 4;
  int m = blockIdx.y * 16 + ty, n = blockIdx.x * 16 + tx;
  float acc = 0.f;
  for (int k0 = 0; k0 < K; k0 += 16) {
    As[ty][tx] = A[m * K + k0 + tx];
    Bs[ty][tx] = Bm[(size_t)(k0 + ty) * N + n];
    __syncthreads();
#pragma unroll
    for (int kk = 0; kk < 16; ++kk) acc += As[ty][kk] * Bs[kk][tx];
    __syncthreads();
  }
  C[m * N + n] = __float2bfloat16(acc);
}

__global__ void k_mm_nn_f32(const float* __restrict__ A, const float* __restrict__ Bm,
                            float* __restrict__ C, int N, int K) {
  __shared__ float As[16][17], Bs[16][17];
  int tx = threadIdx.x & 15, ty = threadIdx.x >> 4;
  int m = blockIdx.y * 16 + ty, n = blockIdx.x * 16 + tx;
  float acc = 0.f;
  for (int k0 = 0; k0 < K; k0 += 16) {
    As[ty][tx] = A[m * K + k0 + tx];
    Bs[ty][tx] = Bm[(size_t)(k0 + ty) * N + n];
    __syncthreads();
#pragma unroll
    for (int kk = 0; kk < 16; ++kk) acc += As[ty][kk] * Bs[kk][tx];
    __syncthreads();
  }
  C[m * N + n] = acc;
}

__global__ void k_mm_nt_f32(const float* __restrict__ A, const float* __restrict__ Bm,
                            float* __restrict__ C, int N, int K) {
  __shared__ float As[16][17], Bs[16][17];
  int tx = threadIdx.x & 15, ty = threadIdx.x >> 4;
  int m = blockIdx.y * 16 + ty;
  int n0 = blockIdx.x * 16;
  float acc = 0.f;
  for (int k0 = 0; k0 < K; k0 += 16) {
    As[ty][tx] = A[m * K + k0 + tx];
    Bs[ty][tx] = Bm[(size_t)(n0 + ty) * K + k0 + tx];
    __syncthreads();
#pragma unroll
    for (int kk = 0; kk < 16; ++kk) acc += As[ty][kk] * Bs[tx][kk];
    __syncthreads();
  }
  C[m * N + n0 + tx] = acc;
}

// -------------------- main ODE integration kernel --------------------
// R14 (best verified: k_main 2374 us). R4 protocol + M-in-registers + fused
// gather + deferred ack + speculative poll. See R13/R14 notes.

__global__ __launch_bounds__(256) void k_main(
    const float* __restrict__ u0, const __hip_bfloat16* __restrict__ Mg,
    const float* __restrict__ cg, const float* __restrict__ b1g,
    const float* __restrict__ dtsg,
    __hip_bfloat16* __restrict__ hG, float* __restrict__ Hacc,
    unsigned int* __restrict__ flags)
{
  __shared__ __hip_bfloat16 hlds[RPC][LPAD];   // 16.25 KB
  __shared__ float dtl[NS];

  const int tid = threadIdx.x;
  const int bx = blockIdx.x;
  const int xcd = bx & 7, slot = bx >> 3;
  const int cl = xcd + ((slot >> 2) << 3);   // cluster members share bid mod 8
  const int jb = slot & 3;
  const int lane = tid & 63, wv = tid >> 6;
  const int r = lane & 15, g4 = lane >> 4;
  const int row0 = cl * RPC;
  const int ub = jb * UBS;
  const int rr = tid >> 4, sl = tid & 15;     // gather assignment

  // ---- M fragments into registers, chunk-reordered: i -> global chunk
  // qg = ((jb + (i>>2)) & 3)*4 + (i&3), so i=0..3 are OWN chunks. ----
  short8 Mreg[2][16];
#pragma unroll
  for (int t = 0; t < 2; ++t)
#pragma unroll
    for (int i = 0; i < 16; ++i) {
      int qg = ((jb + (i >> 2)) & 3) * 4 + (i & 3);
      Mreg[t][i] = *(const short8*)(Mg + (size_t)(ub + wv * 32 + t * 16 + r) * NH
                                    + qg * 32 + g4 * 8);
    }
  if (tid < NS) dtl[tid] = dtsg[tid];

  // per-lane state: (udim = ub + udl0 + t*16 + j, batch row = row0 + r)
  const int udl0 = wv * 32 + g4 * 4;
  float u[2][4], du[2][4], Ht[2][4], hr[2][4], wp[2][4], b1r[2][4], cr[2][4];
#pragma unroll
  for (int t = 0; t < 2; ++t)
#pragma unroll
    for (int j = 0; j < 4; ++j) {
      int ud = ub + udl0 + t * 16 + j;
      u[t][j] = u0[(row0 + r) * NH + ud];
      b1r[t][j] = b1g[ud];
      cr[t][j] = cg[ud];
      Ht[t][j] = 0.f; wp[t][j] = 0.f; du[t][j] = 0.f;
    }
  __syncthreads();

  unsigned int* flg = flags + cl * 32;       // 16 per-wave flag words
  const unsigned int* fp = flg + (lane & 15);
  const bool ownlane = (((lane & 15) >> 2) == jb);   // own block's flag words

  int sidx = 0;
  for (int step = 0; step < NS - 1; ++step) {
    float dt = dtl[step];
#pragma unroll 1
    for (int st = 0; st < 4; ++st, ++sidx) {
      float gam = (st == 0) ? 0.f : ((st == 3) ? dt : 0.5f * dt);
      // h = tanh(u + gam*w_prev + b1)
#pragma unroll
      for (int t = 0; t < 2; ++t)
#pragma unroll
        for (int j = 0; j < 4; ++j)
          hr[t][j] = tanh_fast(u[t][j] + gam * wp[t][j] + b1r[t][j]);

      int par = sidx & 1;
      __hip_bfloat16* hgp = hG + (size_t)(cl * 2 + par) * RPC * NH;
      // publish own h (global stores stay in flight; LDS for own-k MFMA)
#pragma unroll
      for (int t = 0; t < 2; ++t) {
        short4v pk;
        pk.x = (short)bf16bits(hr[t][0]);
        pk.y = (short)bf16bits(hr[t][1]);
        pk.z = (short)bf16bits(hr[t][2]);
        pk.w = (short)bf16bits(hr[t][3]);
        int col = ub + udl0 + t * 16;
        g_store8(hgp + r * NH + col, pk);
        *(short4v*)&hlds[r][col] = pk;
      }
      bar_lgkm();                    // own h visible in LDS; stores in flight

      unsigned tgt = (unsigned)(sidx + 1);
      unsigned specv = g_load4_nw(fp);   // speculative peer-flag load

      // own-k MFMA (publish stores + spec load drain underneath)
      f32x4 acc0 = {0.f, 0.f, 0.f, 0.f}, acc1 = {0.f, 0.f, 0.f, 0.f};
#pragma unroll
      for (int i = 0; i < 4; ++i) {
        int kc = ub + i * 32 + g4 * 8;
        short8 bf = *(const short8*)&hlds[r][kc];
        acc0 = __builtin_amdgcn_mfma_f32_16x16x32_bf16(Mreg[0][i], bf, acc0, 0, 0, 0);
        acc1 = __builtin_amdgcn_mfma_f32_16x16x32_bf16(Mreg[1][i], bf, acc1, 0, 0, 0);
      }

      wait_vm0();                        // ack (residual) + spec load complete
      __builtin_amdgcn_sched_barrier(0); // keep spec check after the wait
      if (lane == 0) g_store4(flg + jb * 4 + wv, tgt);   // per-wave flag

      // peers-only check of speculative value; miss -> proven fused poll loop
      if (!__all((int)(ownlane || (specv >= tgt)))) {
        for (;;) {
          unsigned v = g_load4w(fp);
          if (__all((int)(ownlane || (v >= tgt)))) break;
          __builtin_amdgcn_s_sleep(1);
        }
      }

      // gather 3 remote 4KB chunks: ONE fused asm (loads + wait), then LDS
      {
        int4v d0, d1, d2;
        const __hip_bfloat16* hb = hgp + rr * NH;
        const void* a0 = hb + ((jb + 1) & 3) * UBS + sl * 8;
        const void* a1 = hb + ((jb + 2) & 3) * UBS + sl * 8;
        const void* a2 = hb + ((jb + 3) & 3) * UBS + sl * 8;
        asm volatile(
            "global_load_dwordx4 %0, %3, off sc0 sc1\n\t"
            "global_load_dwordx4 %1, %4, off sc0 sc1\n\t"
            "global_load_dwordx4 %2, %5, off sc0 sc1\n\t"
            "s_waitcnt vmcnt(0)"
            : "=&v"(d0), "=&v"(d1), "=&v"(d2)
            : "v"(a0), "v"(a1), "v"(a2)
            : "memory");
        *(int4v*)&hlds[rr][((jb + 1) & 3) * UBS + sl * 8] = d0;
        *(int4v*)&hlds[rr][((jb + 2) & 3) * UBS + sl * 8] = d1;
        *(int4v*)&hlds[rr][((jb + 3) & 3) * UBS + sl * 8] = d2;
      }
      __syncthreads();                   // remote h visible

      // remote-k MFMA (A from registers, static indices)
#pragma unroll
      for (int m = 1; m < 4; ++m) {
        int jr = (jb + m) & 3;
#pragma unroll
        for (int qq = 0; qq < 4; ++qq) {
          int kc = jr * UBS + qq * 32 + g4 * 8;
          short8 bf = *(const short8*)&hlds[r][kc];
          acc0 = __builtin_amdgcn_mfma_f32_16x16x32_bf16(Mreg[0][m * 4 + qq], bf, acc0, 0, 0, 0);
          acc1 = __builtin_amdgcn_mfma_f32_16x16x32_bf16(Mreg[1][m * 4 + qq], bf, acc1, 0, 0, 0);
        }
      }

      // folded RK4: du += cw*w ; Ht += (dt/6)*cw*h ; wp = w ; st3: u += (dt/6)*du
      {
        float cw = (st == 0 || st == 3) ? 1.f : 2.f;
        float f6 = dt * (1.f / 6.f);
        float f6c = f6 * cw;
#pragma unroll
        for (int j = 0; j < 4; ++j) {
          float w0 = acc0[j] + cr[0][j];
          float w1 = acc1[j] + cr[1][j];
          du[0][j] = (st == 0) ? w0 : du[0][j] + cw * w0;
          du[1][j] = (st == 0) ? w1 : du[1][j] + cw * w1;
          Ht[0][j] += f6c * hr[0][j];
          Ht[1][j] += f6c * hr[1][j];
          wp[0][j] = w0;
          wp[1][j] = w1;
        }
        if (st == 3) {
#pragma unroll
          for (int t = 0; t < 2; ++t)
#pragma unroll
            for (int j = 0; j < 4; ++j)
              u[t][j] += f6 * du[t][j];
        }
      }
    }
  }

  // write out H accumulator
#pragma unroll
  for (int t = 0; t < 2; ++t)
#pragma unroll
    for (int j = 0; j < 4; ++j)
      Hacc[(row0 + r) * NH + ub + udl0 + t * 16 + j] = Ht[t][j];
}

// -------------------- epilogue --------------------
__global__ void k_epi(const float* __restrict__ y0, const float* __restrict__ Hacc,
                      const float* __restrict__ P, const float* __restrict__ Wout,
                      const float* __restrict__ b2, const float* __restrict__ bout,
                      const float* __restrict__ dtsg, float* __restrict__ out)
{
  __shared__ float ys[NH], hs[NH];
  int rr = blockIdx.x, o = threadIdx.x;
  float sdt = dtsg[NS - 1];
  for (int i = threadIdx.x; i < NH; i += blockDim.x) {
    ys[i] = y0[rr * NH + i] + sdt * b2[i];
    hs[i] = Hacc[rr * NH + i];
  }
  __syncthreads();
  float s = bout[o];
  const float* wr = Wout + o * NH;
  const float* pr = P + o * NH;
  for (int d = 0; d < NH; ++d) s += wr[d] * ys[d];
  for (int h = 0; h < NH; ++h) s += pr[h] * hs[h];
  out[rr * NOUT + o] = s;
}

// -------------------- launch --------------------

extern "C" void kernel_launch(void* const* d_in, const int* in_sizes, int n_in,
                              void* d_out, int out_size, void* d_ws, size_t ws_size,
                              hipStream_t stream) {
  const float* x    = (const float*)d_in[0];
  const float* W1   = (const float*)d_in[1];
  const float* b1   = (const float*)d_in[2];
  const float* W2   = (const float*)d_in[3];
  const float* b2   = (const float*)d_in[4];
  const float* Wout = (const float*)d_in[5];
  const float* bout = (const float*)d_in[6];
  float* out = (float*)d_out;

  char* ws = (char*)d_ws;
  float*          dts  = (float*)(ws + OFF_DTS);
  float*          y0   = (float*)(ws + OFF_Y0);
  float*          u0   = (float*)(ws + OFF_U0);
  __hip_bfloat16* Mbf  = (__hip_bfloat16*)(ws + OFF_M);
  float*          cvec = (float*)(ws + OFF_C);
  float*          P    = (float*)(ws + OFF_P);
  __hip_bfloat16* hG   = (__hip_bfloat16*)(ws + OFF_HG);
  float*          Hac  = (float*)(ws + OFF_HACC);
  unsigned int*   flg  = (unsigned int*)(ws + OFF_FLAGS);

  hipMemsetAsync(flg, 0, NCL * 32 * 4, stream);   // monotonic flags start at 0

  k_dts<<<1, 256, 0, stream>>>(x, dts);
  k_y0 <<<NB, 256, 0, stream>>>(x, y0);
  k_c  <<<2, 256, 0, stream>>>(W1, b2, cvec);
  k_mm_nn_bf16<<<dim3(32, 32), 256, 0, stream>>>(W1, W2, Mbf, NH, NH);
  k_mm_nt_f32<<<dim3(32, 16), 256, 0, stream>>>(y0, W1, u0, NH, NH);
  k_mm_nn_f32<<<dim3(32, 8), 256, 0, stream>>>(Wout, W2, P, NH, NH);

  k_main<<<NCL * BPC, 256, 0, stream>>>(u0, Mbf, cvec, b1, dts, hG, Hac, flg);

  k_epi<<<NB, NOUT, 0, stream>>>(y0, Hac, P, Wout, b2, bout, dts, out);
}